// Round 10
// baseline (192.435 us; speedup 1.0000x reference)
//
#include <hip/hip_runtime.h>
#include <hip/hip_bf16.h>
#include <math.h>

#define B_ 2
#define S_ 4096
#define D_ 512
#define H_ 8
#define DK_ 64
#define WIN_ 50
#define NGT 32   // max global chunks (2048 cols; E[G]~780)
#define QSCALE 0.18033688011112042f   // 0.125 * log2(e): softmax in log2 domain

typedef __attribute__((ext_vector_type(8))) _Float16 half8;  // MFMA A/B frag
typedef __attribute__((ext_vector_type(4))) float f32x4;
typedef __attribute__((ext_vector_type(4))) unsigned short us4;
typedef unsigned short ushort_t;

__device__ __forceinline__ unsigned short f2h(float f) {
    _Float16 h = (_Float16)f;                    // v_cvt_f16_f32 (RNE)
    return __builtin_bit_cast(unsigned short, h);
}
// packed f32->f16 convert: lo -> low16, hi -> high16 (v_cvt_pkrtz_f16_f32)
__device__ __forceinline__ unsigned cvt_pk_f16(float lo, float hi) {
    return __builtin_bit_cast(unsigned, __builtin_amdgcn_cvt_pkrtz(lo, hi));
}
// raw v_exp_f32 (2^x), compiler-scheduled
__device__ __forceinline__ float v_exp2(float x) {
    return __builtin_amdgcn_exp2f(x);
}

// ---------------- fused prep: x->fp16, W->fp16, glist -----------------------
__global__ __launch_bounds__(256) void prep_all(const float* __restrict__ x,
                                                const float* __restrict__ W0,
                                                const float* __restrict__ W1,
                                                const float* __restrict__ W2,
                                                const float* __restrict__ W3,
                                                const int* __restrict__ opcode,
                                                ushort_t* __restrict__ xh,
                                                ushort_t* __restrict__ whb,
                                                int* __restrict__ glist,
                                                int* __restrict__ gcount) {
    const int bid = blockIdx.x;
    const int t = threadIdx.x;
    if (bid < 4096) {                       // x -> fp16
        int i = bid * 256 + t;
        f32x4 v = ((const f32x4*)x)[i];
        us4 hv;
        for (int e = 0; e < 4; ++e) hv[e] = f2h(v[e]);
        ((us4*)xh)[i] = hv;
    } else if (bid < 5120) {                // weights -> fp16
        int b2 = bid - 4096;
        int wz = b2 >> 8, inner = b2 & 255;
        const float* src = (wz == 0) ? W0 : (wz == 1) ? W1 : (wz == 2) ? W2 : W3;
        int i = inner * 256 + t;
        f32x4 v = ((const f32x4*)src)[i];
        us4 hv;
        for (int e = 0; e < 4; ++e) hv[e] = f2h(v[e]);
        ((us4*)(whb + (size_t)wz * D_ * D_))[i] = hv;
    } else {                                // glist scan (sorted compact)
        __shared__ int cnts[256];
        unsigned fl = 0; int c = 0;
        for (int k = 0; k < 16; ++k) {
            int col = t * 16 + k;
            int flag = (opcode[col] == 0) | (opcode[S_ + col] == 0);
            fl |= (unsigned)flag << k; c += flag;
        }
        cnts[t] = c;
        __syncthreads();
        for (int off = 1; off < 256; off <<= 1) {
            int v = cnts[t];
            int a = (t >= off) ? cnts[t - off] : 0;
            __syncthreads();
            cnts[t] = v + a;
            __syncthreads();
        }
        int base = cnts[t] - c;
        for (int k = 0; k < 16; ++k)
            if ((fl >> k) & 1) glist[base++] = t * 16 + k;
        int G = cnts[255];
        if (t == 255) gcount[0] = G;
        // pad tail with -1 so attention can load int4 unguarded
        for (int k = 0; k < 8; ++k) {
            int idx = G + t + k * 256;
            if (idx < S_) glist[idx] = -1;
        }
    }
}

// ---------------- fp16 GEMM core (128x128, BK=32, 4 waves, dbuf) ------------
// LDS per buffer (ushort idx): tile(A0/B1)*4096 + kg*1024 + row*8
__device__ __forceinline__ void gemm_core1(const ushort_t* __restrict__ A,
                                           const ushort_t* __restrict__ Bw,
                                           ushort_t (&LDS)[2][8192],
                                           int m0, int n0, int t,
                                           f32x4 (&acc)[4][4]) {
    const int lane = t & 63, wave = t >> 6;
    const int lrow = lane & 15, lkg = lane >> 4;
    const int wr = wave >> 1, wc = wave & 1;
    const ushort_t* srcs[2] = {A, Bw};
    const int row0[2] = {m0, n0};

    auto stage = [&](int buf, int k0) {
        #pragma unroll
        for (int it = 0; it < 4; ++it) {
            int c = it * 4 + wave;
            int tile = c >> 3;
            int kg = (c >> 1) & 3;
            int r = ((c & 1) << 6) | lane;
            const ushort_t* g = srcs[tile] + (size_t)(row0[tile] + r) * 512 + k0 + kg * 8;
            __builtin_amdgcn_global_load_lds(
                (const __attribute__((address_space(1))) void*)g,
                (__attribute__((address_space(3))) void*)(&LDS[buf][c * 512]),
                16, 0, 0);
        }
    };

    stage(0, 0);
    __syncthreads();

    const int aoff = lkg * 1024 + (wr * 64 + lrow) * 8;
    const int boff = 4096 + lkg * 1024 + (wc * 64 + lrow) * 8;
    int cur = 0;
    for (int ks = 0; ks < 16; ++ks) {
        if (ks < 15) stage(cur ^ 1, (ks + 1) * 32);
        const ushort_t* Lb = LDS[cur];
        half8 ah[4], bh[4];
        #pragma unroll
        for (int m = 0; m < 4; ++m) ah[m] = *(const half8*)(Lb + aoff + m * 128);
        #pragma unroll
        for (int n = 0; n < 4; ++n) bh[n] = *(const half8*)(Lb + boff + n * 128);
        #pragma unroll
        for (int m = 0; m < 4; ++m)
            #pragma unroll
            for (int n = 0; n < 4; ++n)
                acc[m][n] = __builtin_amdgcn_mfma_f32_16x16x32_f16(ah[m], bh[n], acc[m][n], 0, 0, 0);
        __syncthreads();
        cur ^= 1;
    }
}

// merged Q/K/V projection: z=0 Q (swapped), z=1 K (swapped), z=2 V (normal)
__global__ __launch_bounds__(256) void gemm_qkv(const ushort_t* __restrict__ xh,
                                                const ushort_t* __restrict__ whb,
                                                const float* __restrict__ bq,
                                                const float* __restrict__ bk,
                                                const float* __restrict__ bv,
                                                ushort_t* __restrict__ qb,
                                                char* __restrict__ bandimg) {
    __shared__ ushort_t LDS[2][8192];
    const int z = blockIdx.z;
    const int t = threadIdx.x;
    const ushort_t* Wz = whb + (size_t)z * D_ * D_;
    const int lane = t & 63, wave = t >> 6;
    const int lrow = lane & 15, lkg = lane >> 4;
    const int wr = wave >> 1, wc = wave & 1;

    f32x4 acc[4][4];
    for (int m = 0; m < 4; ++m)
        for (int n = 0; n < 4; ++n)
            acc[m][n] = f32x4{0.f, 0.f, 0.f, 0.f};

    if (z == 2) {
        // V: A = x rows (s), B = Wv rows (d)
        const int m0 = blockIdx.y * 128, n0 = blockIdx.x * 128;
        gemm_core1(xh, Wz, LDS, m0, n0, t, acc);
        for (int m = 0; m < 4; ++m) {
            int s_base = m0 + wr * 64 + m * 16 + lkg * 4;
            int bb = s_base >> 12, s0 = s_base & (S_ - 1);
            int jt = s0 >> 6, jr0 = s0 & 63;
            for (int n = 0; n < 4; ++n) {
                int col = n0 + wc * 64 + n * 16 + lrow;
                float bs = bv[col];
                int hh = col >> 6, dk = col & 63;
                us4 pk;
                for (int r = 0; r < 4; ++r) pk[r] = f2h(acc[m][n][r] + bs);
                char* img = bandimg + (((size_t)(bb * H_ + hh)) * 64 + jt) * 16384 + 8192;
                *(us4*)(img + ((dk * 128 + jr0 * 2) ^ ((dk & 7) << 4))) = pk;
            }
        }
    } else {
        // Q/K swapped: A = W rows (d), B = x rows (s)
        const int m0 = blockIdx.x * 128, n0 = blockIdx.y * 128;
        gemm_core1(Wz, xh, LDS, m0, n0, t, acc);
        const float* bias = (z == 0) ? bq : bk;
        for (int m = 0; m < 4; ++m) {
            int d_base = m0 + wr * 64 + m * 16 + lkg * 4;
            f32x4 b4 = *(const f32x4*)(bias + d_base);
            int hh = d_base >> 6, dkb = d_base & 63;
            for (int n = 0; n < 4; ++n) {
                int s = n0 + wc * 64 + n * 16 + lrow;
                int bb = s >> 12, sl = s & (S_ - 1);
                us4 pk;
                if (z == 0) {
                    for (int r = 0; r < 4; ++r) pk[r] = f2h((acc[m][n][r] + b4[r]) * QSCALE);
                    *(us4*)(qb + (((size_t)(bb * H_ + hh) * S_) + sl) * DK_ + dkb) = pk;
                } else {
                    for (int r = 0; r < 4; ++r) pk[r] = f2h(acc[m][n][r] + b4[r]);
                    int jt = sl >> 6, jr = sl & 63;
                    char* img = bandimg + (((size_t)(bb * H_ + hh)) * 64 + jt) * 16384;
                    *(us4*)(img + ((jr * 128 + dkb * 2) ^ ((jr & 7) << 4))) = pk;
                }
            }
        }
    }
}

// final projection (swapped, pure fp16): 64(d)x128(s) tiles, 512 blocks
// LDS per buffer: A(Wo) 64x32 at [0..2047], B(ao) 128x32 at [2048..6143]
__global__ __launch_bounds__(256) void gemm_fin(const ushort_t* __restrict__ Woh,
                                                const ushort_t* __restrict__ aoh,
                                                const float* __restrict__ bias,
                                                float* __restrict__ outp) {
    __shared__ ushort_t LDS[2][6144];
    const int t = threadIdx.x;
    const int lane = t & 63, wave = t >> 6;
    const int lrow = lane & 15, lkg = lane >> 4;
    const int wr = wave >> 1, wc = wave & 1;
    const int m0 = blockIdx.x * 64, n0 = blockIdx.y * 128;

    auto stage = [&](int buf, int k0) {
        #pragma unroll
        for (int it = 0; it < 3; ++it) {
            int c = it * 4 + wave;
            const ushort_t* g;
            if (c < 4) {
                g = Woh + (size_t)(m0 + lane) * 512 + k0 + c * 8;       // kg = c
            } else {
                int s2 = c - 4;
                int kg = s2 >> 1, rh = s2 & 1;
                g = aoh + (size_t)(n0 + rh * 64 + lane) * 512 + k0 + kg * 8;
            }
            __builtin_amdgcn_global_load_lds(
                (const __attribute__((address_space(1))) void*)g,
                (__attribute__((address_space(3))) void*)(&LDS[buf][c * 512]),
                16, 0, 0);
        }
    };

    f32x4 acc[2][4];
    for (int m = 0; m < 2; ++m)
        for (int n = 0; n < 4; ++n)
            acc[m][n] = f32x4{0.f, 0.f, 0.f, 0.f};

    stage(0, 0);
    __syncthreads();

    const int aoff = lkg * 512 + (wr * 32 + lrow) * 8;
    const int boff = 2048 + lkg * 1024 + (wc * 64 + lrow) * 8;
    int cur = 0;
    for (int ks = 0; ks < 16; ++ks) {
        if (ks < 15) stage(cur ^ 1, (ks + 1) * 32);
        const ushort_t* Lb = LDS[cur];
        half8 ah[2], bh[4];
        #pragma unroll
        for (int m = 0; m < 2; ++m) ah[m] = *(const half8*)(Lb + aoff + m * 128);
        #pragma unroll
        for (int n = 0; n < 4; ++n) bh[n] = *(const half8*)(Lb + boff + n * 128);
        #pragma unroll
        for (int m = 0; m < 2; ++m)
            #pragma unroll
            for (int n = 0; n < 4; ++n)
                acc[m][n] = __builtin_amdgcn_mfma_f32_16x16x32_f16(ah[m], bh[n], acc[m][n], 0, 0, 0);
        __syncthreads();
        cur ^= 1;
    }

    for (int m = 0; m < 2; ++m) {
        int d_base = m0 + wr * 32 + m * 16 + lkg * 4;
        f32x4 b4 = *(const f32x4*)(bias + d_base);
        for (int n = 0; n < 4; ++n) {
            int s = n0 + wc * 64 + n * 16 + lrow;
            f32x4 o;
            for (int r = 0; r < 4; ++r) o[r] = acc[m][n][r] + b4[r];
            *(f32x4*)(outp + (size_t)s * D_ + d_base) = o;
        }
    }
}

// ---------------- gather global-column chunks into images -------------------
__global__ __launch_bounds__(256) void prep_glob(const char* __restrict__ bandimg,
                                                 char* __restrict__ globimg,
                                                 const int* __restrict__ glist,
                                                 const int* __restrict__ gcount) {
    int G = gcount[0];
    int gc = blockIdx.x;
    if (gc * 64 >= G) return;
    int h = blockIdx.y, b = blockIdx.z;
    int t = threadIdx.x;
    __shared__ int jl[64];
    if (t < 64) { int gi = gc * 64 + t; jl[t] = (gi < G) ? glist[gi] : -1; }
    __syncthreads();
    const size_t bh = (size_t)(b * H_ + h);
    char* dst = globimg + (bh * NGT + gc) * 16384;
    {
        int c = t >> 2, q = t & 3;
        int jj = jl[c];
        #pragma unroll
        for (int p = 0; p < 2; ++p) {
            int o_dst = c * 128 + q * 32 + p * 16;
            __attribute__((ext_vector_type(8))) short val;
            if (jj >= 0) {
                int jr = jj & 63, jt = jj >> 6;
                const char* src = bandimg + (bh * 64 + jt) * 16384;
                val = *(const __attribute__((ext_vector_type(8))) short*)
                      (src + ((jr * 128 + q * 32 + p * 16) ^ ((jr & 7) << 4)));
            } else {
                for (int e = 0; e < 8; ++e) val[e] = 0;
            }
            *(__attribute__((ext_vector_type(8))) short*)(dst + (o_dst ^ ((c & 7) << 4))) = val;
        }
    }
    {
        int d = t >> 2, qq = t & 3;
        __attribute__((ext_vector_type(8))) short v0, v1;
        #pragma unroll 16
        for (int i = 0; i < 16; ++i) {
            int c = qq * 16 + i;
            int jj = jl[c];
            ushort_t val = 0;
            if (jj >= 0) {
                int jr = jj & 63, jt = jj >> 6;
                const char* src = bandimg + (bh * 64 + jt) * 16384 + 8192;
                val = *(const ushort_t*)(src + ((d * 128 + jr * 2) ^ ((d & 7) << 4)));
            }
            if (i < 8) v0[i] = val; else v1[i - 8] = val;
        }
        int o = d * 128 + qq * 32;
        *(__attribute__((ext_vector_type(8))) short*)(dst + 8192 + (o ^ ((d & 7) << 4))) = v0;
        *(__attribute__((ext_vector_type(8))) short*)(dst + 8192 + ((o + 16) ^ ((d & 7) << 4))) = v1;
    }
}

// ---------------- sparse flash attention: 4-wave blocks, defer-rescale ------
// grid: 1-D 1024 blocks; bh = bid & 15 keeps each (b,h)'s images XCD-local.
// 64 q-rows per block, 4 blocks/CU (40KB LDS).
__global__ __launch_bounds__(256) void attn_mfma7(const ushort_t* __restrict__ Qp,
                                                  const char* __restrict__ bandimg,
                                                  const char* __restrict__ globimg,
                                                  const int* __restrict__ glist,
                                                  const int* __restrict__ gcount,
                                                  ushort_t* __restrict__ AO) {
    __shared__ char buf[2][16384];           // [K 8KB][Vt 8KB]
    __shared__ ushort_t Ps[4 * 16 * 64];     // per-wave P^T, swizzled

    const int t = threadIdx.x, lane = t & 63, wave = t >> 6;
    const int q = lane & 15, g = lane >> 4;
    const int bid = blockIdx.x;
    const int bh_lin = bid & 15;              // XCD-local (b,h)
    const int b = bh_lin >> 3, h = bh_lin & 7;
    const int i0 = (bid >> 4) * 64;
    const size_t headoff = ((size_t)(b * H_ + h)) * S_ * DK_;
    const int iq = i0 + wave * 16 + q;
    const int iqm = iq - WIN_;

    half8 qa[2];
    {
        const ushort_t* qrow = Qp + headoff + (size_t)iq * DK_;
        qa[0] = *(const half8*)(qrow + 8 * g);
        qa[1] = *(const half8*)(qrow + 32 + 8 * g);
    }

    f32x4 Oa[4];
    for (int n = 0; n < 4; ++n) Oa[n] = f32x4{0.f, 0.f, 0.f, 0.f};
    float m_st = -1e30f, l_st = 0.f;

    int jlo = i0 - WIN_;
    int jt_lo = (jlo < 0) ? 0 : (jlo >> 6);
    int jhi = i0 + 63 + WIN_; if (jhi > S_ - 1) jhi = S_ - 1;
    int jt_hi = jhi >> 6;
    int nband = jt_hi - jt_lo + 1;
    const int G = gcount[0];
    int nglob = (G + 63) >> 6; if (nglob > NGT) nglob = NGT;
    int nchunk = nband + nglob;

    const size_t bh = (size_t)(b * H_ + h);

    // which glob chunks need the mask? (sorted glist -> range test; partial tail)
    unsigned needmask = 0;
    {
        int wmin = i0 - WIN_, wmax = i0 + 63 + WIN_;
        for (int gc = 0; gc < nglob; ++gc) {
            int lo = glist[gc * 64];
            int hidx = (gc * 64 + 63 < G) ? (gc * 64 + 63) : (G - 1);
            int hi = glist[hidx];
            bool nm = (lo <= wmax && hi >= wmin) || (gc == nglob - 1 && (G & 63));
            needmask |= (unsigned)nm << gc;
        }
    }

    // hoisted LDS offsets (chunk-invariant)
    int koff[4][2], poffw[4], poffr[2];
    #pragma unroll
    for (int n = 0; n < 4; ++n) {
        int row = n * 16 + q;
        #pragma unroll
        for (int kt = 0; kt < 2; ++kt)
            koff[n][kt] = (row * 128 + g * 16 + kt * 64) ^ ((row & 7) << 4);
        poffw[n] = (q * 128 + n * 32 + g * 8) ^ ((q & 7) << 4);
    }
    #pragma unroll
    for (int kt = 0; kt < 2; ++kt)
        poffr[kt] = (q * 128 + g * 16 + kt * 64) ^ ((q & 7) << 4);

    const char* band_base = bandimg + (bh * 64 + jt_lo) * 16384;
    const char* glob_base = globimg + (bh * NGT) * 16384;

    auto stage = [&](int ch, int nb) {
        const char* img = (ch < nband) ? (band_base + (size_t)ch * 16384)
                                       : (glob_base + (size_t)(ch - nband) * 16384);
        #pragma unroll
        for (int i = 0; i < 4; ++i) {
            int seg = wave * 4 + i;
            __builtin_amdgcn_global_load_lds(
                (const __attribute__((address_space(1))) void*)(img + seg * 1024 + lane * 16),
                (__attribute__((address_space(3))) void*)(buf[nb] + seg * 1024),
                16, 0, 0);
        }
    };

    stage(0, 0);
    __syncthreads();

    int cur = 0;
    for (int ch = 0; ch < nchunk; ++ch) {
        if (ch + 1 < nchunk) stage(ch + 1, cur ^ 1);
        const bool isband = ch < nband;
        const int cbase = isband ? (jt_lo + ch) * 64 : 0;
        const int gbase = (ch - nband) * 64;
        const char* Kb = buf[cur];
        const char* Vb = buf[cur] + 8192;

        // QK^T swapped: sc[n][r] = S[j = 16n+4g+r][q]  (log2 domain)
        f32x4 sc[4];
        for (int n = 0; n < 4; ++n) sc[n] = f32x4{0.f, 0.f, 0.f, 0.f};
        __builtin_amdgcn_s_setprio(1);
        #pragma unroll
        for (int n = 0; n < 4; ++n)
            #pragma unroll
            for (int kt = 0; kt < 2; ++kt) {
                half8 ka = *(const half8*)(Kb + koff[n][kt]);
                sc[n] = __builtin_amdgcn_mfma_f32_16x16x32_f16(ka, qa[kt], sc[n], 0, 0, 0);
            }
        __builtin_amdgcn_s_setprio(0);

        // mask (only where needed) + lane-local max
        float pm;
        bool nm = isband || ((needmask >> (ch - nband)) & 1);
        if (nm) {
            pm = -1e30f;
            if (isband) {
                #pragma unroll
                for (int n = 0; n < 4; ++n) {
                    int jb = cbase + n * 16 + 4 * g;
                    #pragma unroll
                    for (int r = 0; r < 4; ++r) {
                        bool inwin = (unsigned)(jb + r - iqm) <= 2 * WIN_;
                        float s = inwin ? sc[n][r] : -1e30f;
                        sc[n][r] = s;
                        pm = fmaxf(pm, s);
                    }
                }
            } else {
                #pragma unroll
                for (int n = 0; n < 4; ++n) {
                    int4 J = *(const int4*)(glist + gbase + n * 16 + g * 4);
                    int js[4] = {J.x, J.y, J.z, J.w};
                    #pragma unroll
                    for (int r = 0; r < 4; ++r) {
                        int jj = js[r];
                        bool inwin = (unsigned)(jj - iqm) <= 2 * WIN_;
                        bool allow = (jj >= 0) && !inwin;
                        float s = allow ? sc[n][r] : -1e30f;
                        sc[n][r] = s;
                        pm = fmaxf(pm, s);
                    }
                }
            }
        } else {
            float a0 = fmaxf(fmaxf(sc[0][0], sc[0][1]), fmaxf(sc[0][2], sc[0][3]));
            float a1 = fmaxf(fmaxf(sc[1][0], sc[1][1]), fmaxf(sc[1][2], sc[1][3]));
            float a2 = fmaxf(fmaxf(sc[2][0], sc[2][1]), fmaxf(sc[2][2], sc[2][3]));
            float a3 = fmaxf(fmaxf(sc[3][0], sc[3][1]), fmaxf(sc[3][2], sc[3][3]));
            pm = fmaxf(fmaxf(a0, a1), fmaxf(a2, a3));
        }
        pm = fmaxf(pm, __shfl_xor(pm, 16, 64));
        pm = fmaxf(pm, __shfl_xor(pm, 32, 64));

        // defer-rescale: only renormalize when max grew by >8 (log2 units).
        // P then bounded by 2^8=256 (fp16-safe); exact after final normalize.
        bool skip = __all(pm <= m_st + 8.0f);
        float fac = 1.0f;
        if (!skip) {
            float mn = fmaxf(m_st, pm);
            fac = v_exp2(m_st - mn);
            m_st = mn;
        }
        float rs = 0.f;
        #pragma unroll
        for (int n = 0; n < 4; ++n)
            #pragma unroll
            for (int r = 0; r < 4; ++r) {
                float p = v_exp2(sc[n][r] - m_st);
                sc[n][r] = p;
                rs += p;
            }
        rs += __shfl_xor(rs, 16, 64);
        rs += __shfl_xor(rs, 32, 64);
        l_st = skip ? (l_st + rs) : (l_st * fac + rs);

        // P^T -> wave-private LDS via v_cvt_pkrtz_f16_f32 (b64 writes)
        ushort_t* Pw = Ps + wave * 1024;
        #pragma unroll
        for (int n = 0; n < 4; ++n) {
            unsigned pk0 = cvt_pk_f16(sc[n][0], sc[n][1]);
            unsigned pk1 = cvt_pk_f16(sc[n][2], sc[n][3]);
            *(unsigned long long*)((char*)Pw + poffw[n]) =
                ((unsigned long long)pk1 << 32) | pk0;
        }

        if (!skip) {
            #pragma unroll
            for (int n = 0; n < 4; ++n)
                #pragma unroll
                for (int r = 0; r < 4; ++r) Oa[n][r] *= fac;
        }

        half8 pa[2];
        #pragma unroll
        for (int kt = 0; kt < 2; ++kt)
            pa[kt] = *(const half8*)((char*)Pw + poffr[kt]);
        __builtin_amdgcn_s_setprio(1);
        #pragma unroll
        for (int n = 0; n < 4; ++n)
            #pragma unroll
            for (int kt = 0; kt < 2; ++kt) {
                half8 va = *(const half8*)(Vb + koff[n][kt]);
                Oa[n] = __builtin_amdgcn_mfma_f32_16x16x32_f16(va, pa[kt], Oa[n], 0, 0, 0);
            }
        __builtin_amdgcn_s_setprio(0);
        __syncthreads();
        cur ^= 1;
    }

    // epilogue: normalize, write fp16 AO
    float inv = 1.0f / l_st;
    #pragma unroll
    for (int n = 0; n < 4; ++n) {
        us4 ph;
        #pragma unroll
        for (int r = 0; r < 4; ++r) ph[r] = f2h(Oa[n][r] * inv);
        size_t base = ((size_t)b * S_ + iq) * D_ + h * DK_ + (n * 16 + g * 4);
        *(us4*)(AO + base) = ph;
    }
}

// ---------------- launch ----------------------------------------------------
extern "C" void kernel_launch(void* const* d_in, const int* in_sizes, int n_in,
                              void* d_out, int out_size, void* d_ws, size_t ws_size,
                              hipStream_t stream) {
    const float* x      = (const float*)d_in[0];
    const int*   opcode = (const int*)d_in[1];
    const float* Wq = (const float*)d_in[2];
    const float* bq = (const float*)d_in[3];
    const float* Wk = (const float*)d_in[4];
    const float* bk = (const float*)d_in[5];
    const float* Wv = (const float*)d_in[6];
    const float* bv = (const float*)d_in[7];
    const float* Wo = (const float*)d_in[8];
    const float* bo = (const float*)d_in[9];
    float* out = (float*)d_out;

    char* ws = (char*)d_ws;
    const size_t bsd = (size_t)B_ * S_ * D_;
    const size_t hf_bytes = bsd * sizeof(ushort_t);                 // 8.39 MB
    const size_t w_bytes  = (size_t)D_ * D_ * sizeof(ushort_t);     // 0.52 MB

    ushort_t* qb = (ushort_t*)(ws);
    ushort_t* xh = (ushort_t*)(ws + hf_bytes);
    ushort_t* ao = xh;                          // reuse after projections
    char* wbase = ws + 2 * hf_bytes;
    ushort_t* whb = (ushort_t*)wbase;           // 4 weights fp16, contiguous
    char* bandimg = wbase + 4 * w_bytes;                         // 16*64*16KB
    char* globimg = bandimg + (size_t)16 * 64 * 16384;           // 16*NGT*16KB
    int* glist  = (int*)(globimg + (size_t)16 * NGT * 16384);
    int* gcount = glist + S_;

    prep_all<<<5121, 256, 0, stream>>>(x, Wq, Wk, Wv, Wo, opcode,
                                       xh, whb, glist, gcount);

    gemm_qkv<<<dim3(D_ / 128, (B_ * S_) / 128, 3), 256, 0, stream>>>(
        xh, whb, bq, bk, bv, qb, bandimg);

    prep_glob<<<dim3(NGT, H_, B_), 256, 0, stream>>>(bandimg, globimg, glist, gcount);

    attn_mfma7<<<dim3(1024), 256, 0, stream>>>(
        qb, bandimg, globimg, glist, gcount, ao);

    gemm_fin<<<dim3(D_ / 64, (B_ * S_) / 128), 256, 0, stream>>>(
        whb + 3 * (size_t)D_ * D_, ao, bo, out);
}

// Round 11
// 184.310 us; speedup vs baseline: 1.0441x; 1.0441x over previous
//
#include <hip/hip_runtime.h>
#include <hip/hip_bf16.h>
#include <math.h>

#define B_ 2
#define S_ 4096
#define D_ 512
#define H_ 8
#define DK_ 64
#define WIN_ 50
#define NGT 32   // max global chunks (2048 cols; E[G]~780)
#define QSCALE 0.18033688011112042f   // 0.125 * log2(e): softmax in log2 domain

typedef __attribute__((ext_vector_type(8))) _Float16 half8;  // MFMA A/B frag
typedef __attribute__((ext_vector_type(4))) float f32x4;
typedef __attribute__((ext_vector_type(4))) unsigned short us4;
typedef unsigned short ushort_t;
typedef unsigned long long u64;

__device__ __forceinline__ unsigned short f2h(float f) {
    _Float16 h = (_Float16)f;                    // v_cvt_f16_f32 (RNE)
    return __builtin_bit_cast(unsigned short, h);
}
// packed f32->f16 convert: lo -> low16, hi -> high16 (v_cvt_pkrtz_f16_f32)
__device__ __forceinline__ unsigned cvt_pk_f16(float lo, float hi) {
    return __builtin_bit_cast(unsigned, __builtin_amdgcn_cvt_pkrtz(lo, hi));
}
__device__ __forceinline__ float v_exp2(float x) {
    return __builtin_amdgcn_exp2f(x);
}

// ---------------- fused prep: x->fp16, W->fp16, glist -----------------------
__global__ __launch_bounds__(256) void prep_all(const float* __restrict__ x,
                                                const float* __restrict__ W0,
                                                const float* __restrict__ W1,
                                                const float* __restrict__ W2,
                                                const float* __restrict__ W3,
                                                const int* __restrict__ opcode,
                                                ushort_t* __restrict__ xh,
                                                ushort_t* __restrict__ whb,
                                                int* __restrict__ glist,
                                                int* __restrict__ gcount) {
    const int bid = blockIdx.x;
    const int t = threadIdx.x;
    if (bid < 4096) {                       // x -> fp16
        int i = bid * 256 + t;
        f32x4 v = ((const f32x4*)x)[i];
        us4 hv;
        for (int e = 0; e < 4; ++e) hv[e] = f2h(v[e]);
        ((us4*)xh)[i] = hv;
    } else if (bid < 5120) {                // weights -> fp16
        int b2 = bid - 4096;
        int wz = b2 >> 8, inner = b2 & 255;
        const float* src = (wz == 0) ? W0 : (wz == 1) ? W1 : (wz == 2) ? W2 : W3;
        int i = inner * 256 + t;
        f32x4 v = ((const f32x4*)src)[i];
        us4 hv;
        for (int e = 0; e < 4; ++e) hv[e] = f2h(v[e]);
        ((us4*)(whb + (size_t)wz * D_ * D_))[i] = hv;
    } else {                                // glist scan (sorted compact)
        __shared__ int cnts[256];
        unsigned fl = 0; int c = 0;
        for (int k = 0; k < 16; ++k) {
            int col = t * 16 + k;
            int flag = (opcode[col] == 0) | (opcode[S_ + col] == 0);
            fl |= (unsigned)flag << k; c += flag;
        }
        cnts[t] = c;
        __syncthreads();
        for (int off = 1; off < 256; off <<= 1) {
            int v = cnts[t];
            int a = (t >= off) ? cnts[t - off] : 0;
            __syncthreads();
            cnts[t] = v + a;
            __syncthreads();
        }
        int base = cnts[t] - c;
        for (int k = 0; k < 16; ++k)
            if ((fl >> k) & 1) glist[base++] = t * 16 + k;
        int G = cnts[255];
        if (t == 255) gcount[0] = G;
        for (int k = 0; k < 8; ++k) {
            int idx = G + t + k * 256;
            if (idx < S_) glist[idx] = -1;
        }
    }
}

// ---------------- fp16 GEMM core (128x128, BK=32, 4 waves, dbuf) ------------
__device__ __forceinline__ void gemm_core1(const ushort_t* __restrict__ A,
                                           const ushort_t* __restrict__ Bw,
                                           ushort_t (&LDS)[2][8192],
                                           int m0, int n0, int t,
                                           f32x4 (&acc)[4][4]) {
    const int lane = t & 63, wave = t >> 6;
    const int lrow = lane & 15, lkg = lane >> 4;
    const int wr = wave >> 1, wc = wave & 1;
    const ushort_t* srcs[2] = {A, Bw};
    const int row0[2] = {m0, n0};

    auto stage = [&](int buf, int k0) {
        #pragma unroll
        for (int it = 0; it < 4; ++it) {
            int c = it * 4 + wave;
            int tile = c >> 3;
            int kg = (c >> 1) & 3;
            int r = ((c & 1) << 6) | lane;
            const ushort_t* g = srcs[tile] + (size_t)(row0[tile] + r) * 512 + k0 + kg * 8;
            __builtin_amdgcn_global_load_lds(
                (const __attribute__((address_space(1))) void*)g,
                (__attribute__((address_space(3))) void*)(&LDS[buf][c * 512]),
                16, 0, 0);
        }
    };

    stage(0, 0);
    __syncthreads();

    const int aoff = lkg * 1024 + (wr * 64 + lrow) * 8;
    const int boff = 4096 + lkg * 1024 + (wc * 64 + lrow) * 8;
    int cur = 0;
    for (int ks = 0; ks < 16; ++ks) {
        if (ks < 15) stage(cur ^ 1, (ks + 1) * 32);
        const ushort_t* Lb = LDS[cur];
        half8 ah[4], bh[4];
        #pragma unroll
        for (int m = 0; m < 4; ++m) ah[m] = *(const half8*)(Lb + aoff + m * 128);
        #pragma unroll
        for (int n = 0; n < 4; ++n) bh[n] = *(const half8*)(Lb + boff + n * 128);
        #pragma unroll
        for (int m = 0; m < 4; ++m)
            #pragma unroll
            for (int n = 0; n < 4; ++n)
                acc[m][n] = __builtin_amdgcn_mfma_f32_16x16x32_f16(ah[m], bh[n], acc[m][n], 0, 0, 0);
        __syncthreads();
        cur ^= 1;
    }
}

// merged Q/K/V projection with COALESCED epilogues (LDS transpose).
// z=0 Q (swapped), z=1 K (swapped), z=2 V (normal).
__global__ __launch_bounds__(256) void gemm_qkv(const ushort_t* __restrict__ xh,
                                                const ushort_t* __restrict__ whb,
                                                const float* __restrict__ bq,
                                                const float* __restrict__ bk,
                                                const float* __restrict__ bv,
                                                ushort_t* __restrict__ qb,
                                                char* __restrict__ bandimg) {
    __shared__ ushort_t LDS[2][8192];       // 32KB; reused as 128x128 fp16 tile
    const int z = blockIdx.z;
    const int t = threadIdx.x;
    const ushort_t* Wz = whb + (size_t)z * D_ * D_;
    const int lane = t & 63, wave = t >> 6;
    const int lrow = lane & 15, lkg = lane >> 4;
    const int wr = wave >> 1, wc = wave & 1;

    f32x4 acc[4][4];
    for (int m = 0; m < 4; ++m)
        for (int n = 0; n < 4; ++n)
            acc[m][n] = f32x4{0.f, 0.f, 0.f, 0.f};

    char* Lf = (char*)LDS;

    if (z == 2) {
        // V: A = x rows (s), B = Wv rows (d). LDS tile [d_local][s_local].
        const int m0 = blockIdx.y * 128, n0 = blockIdx.x * 128;
        gemm_core1(xh, Wz, LDS, m0, n0, t, acc);
        // acc[m][n][r]: s_local = wr*64+m*16+lkg*4+r, d_local = wc*64+n*16+lrow
        #pragma unroll
        for (int n = 0; n < 4; ++n) {
            int dl = wc * 64 + n * 16 + lrow;
            float bs = bv[n0 + dl];
            #pragma unroll
            for (int m = 0; m < 4; ++m) {
                int sl = wr * 64 + m * 16 + lkg * 4;
                unsigned pk0 = cvt_pk_f16(acc[m][n][0] + bs, acc[m][n][1] + bs);
                unsigned pk1 = cvt_pk_f16(acc[m][n][2] + bs, acc[m][n][3] + bs);
                int off = (dl * 256 + sl * 2) ^ ((dl & 15) << 4);
                *(u64*)(Lf + off) = ((u64)pk1 << 32) | pk0;
            }
        }
        __syncthreads();
        // read-out: rows = (head hd, jt half jh, dk); 2048 16B pieces
        int bb = m0 >> 12;
        int jt0 = (m0 & (S_ - 1)) >> 6;
        #pragma unroll
        for (int i = 0; i < 8; ++i) {
            int L = t + 256 * i;
            int hd = L >> 10, rem = L & 1023;
            int jh = rem >> 9, dk = (rem >> 3) & 63, p = rem & 7;
            int dl = hd * 64 + dk;
            int off = (dl * 256 + jh * 128 + p * 16) ^ ((dl & 15) << 4);
            f32x4 v = *(const f32x4*)(Lf + off);
            int hh = (n0 >> 6) + hd;
            char* img = bandimg + (((size_t)(bb * H_ + hh)) * 64 + jt0 + jh) * 16384 + 8192;
            *(f32x4*)(img + ((dk * 128 + p * 16) ^ ((dk & 7) << 4))) = v;
        }
    } else {
        // Q/K swapped: A = W rows (d), B = x rows (s). LDS tile [s_local][d_local].
        const int m0 = blockIdx.x * 128, n0 = blockIdx.y * 128;
        gemm_core1(Wz, xh, LDS, m0, n0, t, acc);
        const float* bias = (z == 0) ? bq : bk;
        const float scale = (z == 0) ? QSCALE : 1.0f;
        #pragma unroll
        for (int m = 0; m < 4; ++m) {
            int dl = wr * 64 + m * 16 + lkg * 4;   // + r
            f32x4 b4 = *(const f32x4*)(bias + m0 + dl);
            #pragma unroll
            for (int n = 0; n < 4; ++n) {
                int sl = wc * 64 + n * 16 + lrow;
                float v0 = (acc[m][n][0] + b4[0]) * scale;
                float v1 = (acc[m][n][1] + b4[1]) * scale;
                float v2 = (acc[m][n][2] + b4[2]) * scale;
                float v3 = (acc[m][n][3] + b4[3]) * scale;
                unsigned pk0 = cvt_pk_f16(v0, v1);
                unsigned pk1 = cvt_pk_f16(v2, v3);
                int off = (sl * 256 + dl * 2) ^ ((sl & 15) << 4);
                *(u64*)(Lf + off) = ((u64)pk1 << 32) | pk0;
            }
        }
        __syncthreads();
        int bb = n0 >> 12;
        int s0 = n0 & (S_ - 1);
        #pragma unroll
        for (int i = 0; i < 8; ++i) {
            int L = t + 256 * i;
            int hd = L >> 10, sl = (L >> 3) & 127, p = L & 7;
            int off = (sl * 256 + hd * 128 + p * 16) ^ ((sl & 15) << 4);
            f32x4 v = *(const f32x4*)(Lf + off);
            int hh = (m0 >> 6) + hd;
            if (z == 0) {
                char* dst = (char*)qb + (((size_t)(bb * H_ + hh) * S_) + s0 + sl) * DK_ * 2;
                *(f32x4*)(dst + p * 16) = v;
            } else {
                int sg = s0 + sl;
                int jt = sg >> 6, jr = sg & 63;
                char* img = bandimg + (((size_t)(bb * H_ + hh)) * 64 + jt) * 16384;
                *(f32x4*)(img + ((jr * 128 + p * 16) ^ ((jr & 7) << 4))) = v;
            }
        }
    }
}

// final projection (swapped, fp16), coalesced epilogue via LDS fp32 tile.
__global__ __launch_bounds__(256) void gemm_fin(const ushort_t* __restrict__ Woh,
                                                const ushort_t* __restrict__ aoh,
                                                const float* __restrict__ bias,
                                                float* __restrict__ outp) {
    __shared__ char LDSF[32768];            // staging: first 24KB; epilogue: 32KB
    ushort_t (&LDS)[2][6144] = *reinterpret_cast<ushort_t(*)[2][6144]>(LDSF);
    const int t = threadIdx.x;
    const int lane = t & 63, wave = t >> 6;
    const int lrow = lane & 15, lkg = lane >> 4;
    const int wr = wave >> 1, wc = wave & 1;
    const int m0 = blockIdx.x * 64, n0 = blockIdx.y * 128;

    auto stage = [&](int buf, int k0) {
        #pragma unroll
        for (int it = 0; it < 3; ++it) {
            int c = it * 4 + wave;
            const ushort_t* g;
            if (c < 4) {
                g = Woh + (size_t)(m0 + lane) * 512 + k0 + c * 8;
            } else {
                int s2 = c - 4;
                int kg = s2 >> 1, rh = s2 & 1;
                g = aoh + (size_t)(n0 + rh * 64 + lane) * 512 + k0 + kg * 8;
            }
            __builtin_amdgcn_global_load_lds(
                (const __attribute__((address_space(1))) void*)g,
                (__attribute__((address_space(3))) void*)(&LDS[buf][c * 512]),
                16, 0, 0);
        }
    };

    f32x4 acc[2][4];
    for (int m = 0; m < 2; ++m)
        for (int n = 0; n < 4; ++n)
            acc[m][n] = f32x4{0.f, 0.f, 0.f, 0.f};

    stage(0, 0);
    __syncthreads();

    const int aoff = lkg * 512 + (wr * 32 + lrow) * 8;
    const int boff = 2048 + lkg * 1024 + (wc * 64 + lrow) * 8;
    int cur = 0;
    for (int ks = 0; ks < 16; ++ks) {
        if (ks < 15) stage(cur ^ 1, (ks + 1) * 32);
        const ushort_t* Lb = LDS[cur];
        half8 ah[2], bh[4];
        #pragma unroll
        for (int m = 0; m < 2; ++m) ah[m] = *(const half8*)(Lb + aoff + m * 128);
        #pragma unroll
        for (int n = 0; n < 4; ++n) bh[n] = *(const half8*)(Lb + boff + n * 128);
        #pragma unroll
        for (int m = 0; m < 2; ++m)
            #pragma unroll
            for (int n = 0; n < 4; ++n)
                acc[m][n] = __builtin_amdgcn_mfma_f32_16x16x32_f16(ah[m], bh[n], acc[m][n], 0, 0, 0);
        __syncthreads();
        cur ^= 1;
    }

    // epilogue: LDS [s_local 128][d_local 64] f32, then coalesced 16B stores
    #pragma unroll
    for (int m = 0; m < 2; ++m) {
        int dl = wr * 32 + m * 16 + lkg * 4;   // + r
        f32x4 b4 = *(const f32x4*)(bias + m0 + dl);
        #pragma unroll
        for (int n = 0; n < 4; ++n) {
            int sl = wc * 64 + n * 16 + lrow;
            f32x4 o;
            for (int r = 0; r < 4; ++r) o[r] = acc[m][n][r] + b4[r];
            *(f32x4*)(LDSF + ((sl * 256 + dl * 4) ^ ((sl & 15) << 4))) = o;
        }
    }
    __syncthreads();
    #pragma unroll
    for (int i = 0; i < 8; ++i) {
        int L = t + 256 * i;
        int sl = L >> 4, p = L & 15;
        f32x4 v = *(const f32x4*)(LDSF + ((sl * 256 + p * 16) ^ ((sl & 15) << 4)));
        char* dst = (char*)outp + ((size_t)(n0 + sl) * 512 + m0) * 4;
        *(f32x4*)(dst + p * 16) = v;
    }
}

// ---------------- gather global-column chunks into images -------------------
__global__ __launch_bounds__(256) void prep_glob(const char* __restrict__ bandimg,
                                                 char* __restrict__ globimg,
                                                 const int* __restrict__ glist,
                                                 const int* __restrict__ gcount) {
    int G = gcount[0];
    int gc = blockIdx.x;
    if (gc * 64 >= G) return;
    int h = blockIdx.y, b = blockIdx.z;
    int t = threadIdx.x;
    __shared__ int jl[64];
    if (t < 64) { int gi = gc * 64 + t; jl[t] = (gi < G) ? glist[gi] : -1; }
    __syncthreads();
    const size_t bh = (size_t)(b * H_ + h);
    char* dst = globimg + (bh * NGT + gc) * 16384;
    {
        int c = t >> 2, q = t & 3;
        int jj = jl[c];
        #pragma unroll
        for (int p = 0; p < 2; ++p) {
            int o_dst = c * 128 + q * 32 + p * 16;
            __attribute__((ext_vector_type(8))) short val;
            if (jj >= 0) {
                int jr = jj & 63, jt = jj >> 6;
                const char* src = bandimg + (bh * 64 + jt) * 16384;
                val = *(const __attribute__((ext_vector_type(8))) short*)
                      (src + ((jr * 128 + q * 32 + p * 16) ^ ((jr & 7) << 4)));
            } else {
                for (int e = 0; e < 8; ++e) val[e] = 0;
            }
            *(__attribute__((ext_vector_type(8))) short*)(dst + (o_dst ^ ((c & 7) << 4))) = val;
        }
    }
    {
        int d = t >> 2, qq = t & 3;
        __attribute__((ext_vector_type(8))) short v0, v1;
        #pragma unroll 16
        for (int i = 0; i < 16; ++i) {
            int c = qq * 16 + i;
            int jj = jl[c];
            ushort_t val = 0;
            if (jj >= 0) {
                int jr = jj & 63, jt = jj >> 6;
                const char* src = bandimg + (bh * 64 + jt) * 16384 + 8192;
                val = *(const ushort_t*)(src + ((d * 128 + jr * 2) ^ ((d & 7) << 4)));
            }
            if (i < 8) v0[i] = val; else v1[i - 8] = val;
        }
        int o = d * 128 + qq * 32;
        *(__attribute__((ext_vector_type(8))) short*)(dst + 8192 + (o ^ ((d & 7) << 4))) = v0;
        *(__attribute__((ext_vector_type(8))) short*)(dst + 8192 + ((o + 16) ^ ((d & 7) << 4))) = v1;
    }
}

// ---------------- sparse flash attention: 8-wave, defer-rescale, coalesced --
// grid: 1-D 512 blocks; bh = bid & 15 keeps each (b,h)'s images XCD-local.
__global__ __launch_bounds__(512) void attn_mfma8(const ushort_t* __restrict__ Qp,
                                                  const char* __restrict__ bandimg,
                                                  const char* __restrict__ globimg,
                                                  const int* __restrict__ glist,
                                                  const int* __restrict__ gcount,
                                                  ushort_t* __restrict__ AO) {
    __shared__ char buf[2][16384];           // [K 8KB][Vt 8KB]
    __shared__ ushort_t Ps[8 * 16 * 64];     // per-wave P^T; reused as O tile

    const int t = threadIdx.x, lane = t & 63, wave = t >> 6;
    const int q = lane & 15, g = lane >> 4;
    const int bid = blockIdx.x;
    const int bh_lin = bid & 15;              // XCD-local (b,h)
    const int b = bh_lin >> 3, h = bh_lin & 7;
    const int i0 = (bid >> 4) * 128;
    const size_t headoff = ((size_t)(b * H_ + h)) * S_ * DK_;
    const int iq = i0 + wave * 16 + q;
    const int iqm = iq - WIN_;

    half8 qa[2];
    {
        const ushort_t* qrow = Qp + headoff + (size_t)iq * DK_;
        qa[0] = *(const half8*)(qrow + 8 * g);
        qa[1] = *(const half8*)(qrow + 32 + 8 * g);
    }

    f32x4 Oa[4];
    for (int n = 0; n < 4; ++n) Oa[n] = f32x4{0.f, 0.f, 0.f, 0.f};
    float m_st = -1e30f, l_st = 0.f;

    int jlo = i0 - WIN_;
    int jt_lo = (jlo < 0) ? 0 : (jlo >> 6);
    int jhi = i0 + 127 + WIN_; if (jhi > S_ - 1) jhi = S_ - 1;
    int jt_hi = jhi >> 6;
    int nband = jt_hi - jt_lo + 1;
    const int G = gcount[0];
    int nglob = (G + 63) >> 6; if (nglob > NGT) nglob = NGT;
    int nchunk = nband + nglob;

    const size_t bh = (size_t)(b * H_ + h);

    unsigned needmask = 0;
    {
        int wmin = i0 - WIN_, wmax = i0 + 127 + WIN_;
        for (int gc = 0; gc < nglob; ++gc) {
            int lo = glist[gc * 64];
            int hidx = (gc * 64 + 63 < G) ? (gc * 64 + 63) : (G - 1);
            int hi = glist[hidx];
            bool nm = (lo <= wmax && hi >= wmin) || (gc == nglob - 1 && (G & 63));
            needmask |= (unsigned)nm << gc;
        }
    }

    int koff[4][2], poffw[4], poffr[2];
    #pragma unroll
    for (int n = 0; n < 4; ++n) {
        int row = n * 16 + q;
        #pragma unroll
        for (int kt = 0; kt < 2; ++kt)
            koff[n][kt] = (row * 128 + g * 16 + kt * 64) ^ ((row & 7) << 4);
        poffw[n] = (q * 128 + n * 32 + g * 8) ^ ((q & 7) << 4);
    }
    #pragma unroll
    for (int kt = 0; kt < 2; ++kt)
        poffr[kt] = (q * 128 + g * 16 + kt * 64) ^ ((q & 7) << 4);

    const char* band_base = bandimg + (bh * 64 + jt_lo) * 16384;
    const char* glob_base = globimg + (bh * NGT) * 16384;

    auto stage = [&](int ch, int nb) {
        const char* img = (ch < nband) ? (band_base + (size_t)ch * 16384)
                                       : (glob_base + (size_t)(ch - nband) * 16384);
        #pragma unroll
        for (int i = 0; i < 2; ++i) {
            int seg = wave * 2 + i;
            __builtin_amdgcn_global_load_lds(
                (const __attribute__((address_space(1))) void*)(img + seg * 1024 + lane * 16),
                (__attribute__((address_space(3))) void*)(buf[nb] + seg * 1024),
                16, 0, 0);
        }
    };

    stage(0, 0);
    __syncthreads();

    int cur = 0;
    for (int ch = 0; ch < nchunk; ++ch) {
        if (ch + 1 < nchunk) stage(ch + 1, cur ^ 1);
        const bool isband = ch < nband;
        const int cbase = isband ? (jt_lo + ch) * 64 : 0;
        const int gbase = (ch - nband) * 64;
        const char* Kb = buf[cur];
        const char* Vb = buf[cur] + 8192;

        f32x4 sc[4];
        for (int n = 0; n < 4; ++n) sc[n] = f32x4{0.f, 0.f, 0.f, 0.f};
        __builtin_amdgcn_s_setprio(1);
        #pragma unroll
        for (int n = 0; n < 4; ++n)
            #pragma unroll
            for (int kt = 0; kt < 2; ++kt) {
                half8 ka = *(const half8*)(Kb + koff[n][kt]);
                sc[n] = __builtin_amdgcn_mfma_f32_16x16x32_f16(ka, qa[kt], sc[n], 0, 0, 0);
            }
        __builtin_amdgcn_s_setprio(0);

        float pm;
        bool nm = isband || ((needmask >> (ch - nband)) & 1);
        if (nm) {
            pm = -1e30f;
            if (isband) {
                #pragma unroll
                for (int n = 0; n < 4; ++n) {
                    int jb = cbase + n * 16 + 4 * g;
                    #pragma unroll
                    for (int r = 0; r < 4; ++r) {
                        bool inwin = (unsigned)(jb + r - iqm) <= 2 * WIN_;
                        float s = inwin ? sc[n][r] : -1e30f;
                        sc[n][r] = s;
                        pm = fmaxf(pm, s);
                    }
                }
            } else {
                #pragma unroll
                for (int n = 0; n < 4; ++n) {
                    int4 J = *(const int4*)(glist + gbase + n * 16 + g * 4);
                    int js[4] = {J.x, J.y, J.z, J.w};
                    #pragma unroll
                    for (int r = 0; r < 4; ++r) {
                        int jj = js[r];
                        bool inwin = (unsigned)(jj - iqm) <= 2 * WIN_;
                        bool allow = (jj >= 0) && !inwin;
                        float s = allow ? sc[n][r] : -1e30f;
                        sc[n][r] = s;
                        pm = fmaxf(pm, s);
                    }
                }
            }
        } else {
            float a0 = fmaxf(fmaxf(sc[0][0], sc[0][1]), fmaxf(sc[0][2], sc[0][3]));
            float a1 = fmaxf(fmaxf(sc[1][0], sc[1][1]), fmaxf(sc[1][2], sc[1][3]));
            float a2 = fmaxf(fmaxf(sc[2][0], sc[2][1]), fmaxf(sc[2][2], sc[2][3]));
            float a3 = fmaxf(fmaxf(sc[3][0], sc[3][1]), fmaxf(sc[3][2], sc[3][3]));
            pm = fmaxf(fmaxf(a0, a1), fmaxf(a2, a3));
        }
        pm = fmaxf(pm, __shfl_xor(pm, 16, 64));
        pm = fmaxf(pm, __shfl_xor(pm, 32, 64));

        // defer-rescale: renormalize only when max grew by >8 (log2 units).
        bool skip = __all(pm <= m_st + 8.0f);
        float fac = 1.0f;
        if (!skip) {
            float mn = fmaxf(m_st, pm);
            fac = v_exp2(m_st - mn);
            m_st = mn;
        }
        float rs = 0.f;
        #pragma unroll
        for (int n = 0; n < 4; ++n)
            #pragma unroll
            for (int r = 0; r < 4; ++r) {
                float p = v_exp2(sc[n][r] - m_st);
                sc[n][r] = p;
                rs += p;
            }
        rs += __shfl_xor(rs, 16, 64);
        rs += __shfl_xor(rs, 32, 64);
        l_st = skip ? (l_st + rs) : (l_st * fac + rs);

        ushort_t* Pw = Ps + wave * 1024;
        #pragma unroll
        for (int n = 0; n < 4; ++n) {
            unsigned pk0 = cvt_pk_f16(sc[n][0], sc[n][1]);
            unsigned pk1 = cvt_pk_f16(sc[n][2], sc[n][3]);
            *(u64*)((char*)Pw + poffw[n]) = ((u64)pk1 << 32) | pk0;
        }

        if (!skip) {
            #pragma unroll
            for (int n = 0; n < 4; ++n)
                #pragma unroll
                for (int r = 0; r < 4; ++r) Oa[n][r] *= fac;
        }

        half8 pa[2];
        #pragma unroll
        for (int kt = 0; kt < 2; ++kt)
            pa[kt] = *(const half8*)((char*)Pw + poffr[kt]);
        __builtin_amdgcn_s_setprio(1);
        #pragma unroll
        for (int n = 0; n < 4; ++n)
            #pragma unroll
            for (int kt = 0; kt < 2; ++kt) {
                half8 va = *(const half8*)(Vb + koff[n][kt]);
                Oa[n] = __builtin_amdgcn_mfma_f32_16x16x32_f16(va, pa[kt], Oa[n], 0, 0, 0);
            }
        __builtin_amdgcn_s_setprio(0);
        __syncthreads();
        cur ^= 1;
    }

    // epilogue: O -> Ps as [row 128][dk 64] fp16 (swizzled), then coalesced
    float inv = 1.0f / l_st;
    {
        ushort_t* Pw = Ps + wave * 1024;
        #pragma unroll
        for (int n = 0; n < 4; ++n) {
            unsigned pk0 = cvt_pk_f16(Oa[n][0] * inv, Oa[n][1] * inv);
            unsigned pk1 = cvt_pk_f16(Oa[n][2] * inv, Oa[n][3] * inv);
            *(u64*)((char*)Pw + poffw[n]) = ((u64)pk1 << 32) | pk0;
        }
    }
    __syncthreads();
    {
        const char* Pb = (const char*)Ps;
        #pragma unroll
        for (int i = 0; i < 2; ++i) {
            int L = t + i * 512;            // 0..1023
            int row = L >> 3, p = L & 7;
            int off = (row * 128 + p * 16) ^ ((row & 7) << 4);
            f32x4 v = *(const f32x4*)(Pb + off);
            char* dst = (char*)AO + (((size_t)b * S_ + i0 + row) * D_ + h * DK_) * 2;
            *(f32x4*)(dst + p * 16) = v;
        }
    }
}

// ---------------- launch ----------------------------------------------------
extern "C" void kernel_launch(void* const* d_in, const int* in_sizes, int n_in,
                              void* d_out, int out_size, void* d_ws, size_t ws_size,
                              hipStream_t stream) {
    const float* x      = (const float*)d_in[0];
    const int*   opcode = (const int*)d_in[1];
    const float* Wq = (const float*)d_in[2];
    const float* bq = (const float*)d_in[3];
    const float* Wk = (const float*)d_in[4];
    const float* bk = (const float*)d_in[5];
    const float* Wv = (const float*)d_in[6];
    const float* bv = (const float*)d_in[7];
    const float* Wo = (const float*)d_in[8];
    const float* bo = (const float*)d_in[9];
    float* out = (float*)d_out;

    char* ws = (char*)d_ws;
    const size_t bsd = (size_t)B_ * S_ * D_;
    const size_t hf_bytes = bsd * sizeof(ushort_t);                 // 8.39 MB
    const size_t w_bytes  = (size_t)D_ * D_ * sizeof(ushort_t);     // 0.52 MB

    ushort_t* qb = (ushort_t*)(ws);
    ushort_t* xh = (ushort_t*)(ws + hf_bytes);
    ushort_t* ao = xh;                          // reuse after projections
    char* wbase = ws + 2 * hf_bytes;
    ushort_t* whb = (ushort_t*)wbase;           // 4 weights fp16, contiguous
    char* bandimg = wbase + 4 * w_bytes;                         // 16*64*16KB
    char* globimg = bandimg + (size_t)16 * 64 * 16384;           // 16*NGT*16KB
    int* glist  = (int*)(globimg + (size_t)16 * NGT * 16384);
    int* gcount = glist + S_;

    prep_all<<<5121, 256, 0, stream>>>(x, Wq, Wk, Wv, Wo, opcode,
                                       xh, whb, glist, gcount);

    gemm_qkv<<<dim3(D_ / 128, (B_ * S_) / 128, 3), 256, 0, stream>>>(
        xh, whb, bq, bk, bv, qb, bandimg);

    prep_glob<<<dim3(NGT, H_, B_), 256, 0, stream>>>(bandimg, globimg, glist, gcount);

    attn_mfma8<<<dim3(512), 512, 0, stream>>>(
        qb, bandimg, globimg, glist, gcount, ao);

    gemm_fin<<<dim3(D_ / 64, (B_ * S_) / 128), 256, 0, stream>>>(
        whb + 3 * (size_t)D_ * D_, ao, bo, out);
}